// Round 2
// baseline (322.386 us; speedup 1.0000x reference)
//
#include <hip/hip_runtime.h>

#define IMG_H 64
#define IMG_W 64
#define TH 16
#define TW 32
#define INH 21   // input rows staged: ty0-4 .. ty0+16
#define INW 40   // input cols staged: tx0-4 .. tx0+35
#define INS 41   // padded LDS stride
#define H1H 18   // h1 rows: ty0-1 .. ty0+16
#define H1W 34   // h1 cols: tx0-1 .. tx0+32

__device__ __forceinline__ float bf_lo(unsigned u) { return __uint_as_float(u << 16); }
__device__ __forceinline__ float bf_hi(unsigned u) { return __uint_as_float(u & 0xffff0000u); }
__device__ __forceinline__ unsigned bf_rne(float f) {
    unsigned u = __float_as_uint(f);
    return (u + 0x7fffu + ((u >> 16) & 1u)) >> 16;
}

__global__ __launch_bounds__(256, 4) void pixelcnn_fused(
    const float* __restrict__ x,
    const float* __restrict__ w1, const float* __restrict__ b1,
    const float* __restrict__ w2, const float* __restrict__ b2,
    const float* __restrict__ w3, const float* __restrict__ b3,
    float* __restrict__ out)
{
    // LDS: ~38 KB total -> 4 blocks/CU
    __shared__ __align__(16) float s_in[INH * INS];          // 3444 B
    __shared__ __align__(16) float s_w1[24 * 16];            // [tap][c] 1536 B
    __shared__ __align__(16) float s_w2[5 * 16 * 16];        // [tap][i][o] 5120 B
    __shared__ __align__(16) float s_w3[16];
    __shared__ __align__(16) float s_b1[16];
    __shared__ __align__(16) float s_b2[16];
    __shared__ __align__(16) unsigned s_h1[2 * H1H * H1W * 4]; // bf16 h1: [g2][y][x][8ch] 19584 B
    __shared__ __align__(16) float s_red[4 * TH * TW];       // per-wave partials, 8192 B

    const int t = threadIdx.x;
    const int lane = t & 63;
    const int wave = t >> 6;
    const int img = blockIdx.y;
    const int tile = blockIdx.x;
    const int ty0 = (tile >> 1) * TH;
    const int tx0 = (tile & 1) * TW;

    const float* xim = x + img * (IMG_H * IMG_W);

    // ---------------- Phase 0: stage input + weights (256 threads!) ----------------
    for (int idx = t; idx < INH * INW; idx += 256) {
        int r = idx / INW, c = idx - r * INW;
        int gy = ty0 - 4 + r, gx = tx0 - 4 + c;
        float v = 0.f;
        if ((unsigned)gy < IMG_H && (unsigned)gx < IMG_W) v = xim[gy * IMG_W + gx];
        s_in[r * INS + c] = v;
    }
    for (int idx = t; idx < 24 * 16; idx += 256) {   // masked w1 taps: flat offsets 0..23
        int k = idx >> 4, c = idx & 15;
        s_w1[idx] = w1[c * 49 + k];
    }
    if (t < 16) {
        s_w3[t] = w3[t];
        s_b1[t] = b1[t];
        s_b2[t] = b2[t];
    }
    for (int idx = t; idx < 5 * 16 * 16; idx += 256) {  // masked w2 taps: flat offsets 0..4
        int k = idx >> 8, i = (idx >> 4) & 15, o = idx & 15;
        s_w2[idx] = w2[(o * 16 + i) * 9 + k];
    }
    __syncthreads();

    // ---------------- Phase 1: L1 7x7 masked conv -> ReLU -> bf16 LDS ----------------
    {
        const int g = wave;              // 4-channel group
        const int g2 = g >> 1, half = g & 1;
        const float4* w1v = (const float4*)s_w1;     // [tap][4 groups]
        const float4 bias = ((const float4*)s_b1)[g];
        for (int p = lane; p < H1H * H1W; p += 64) {
            int y = p / H1W, xx = p - y * H1W;
            int gy = ty0 - 1 + y, gx = tx0 - 1 + xx;
            uint2 packed;
            if ((unsigned)gy < IMG_H && (unsigned)gx < IMG_W) {
                float4 acc = bias;
#pragma unroll
                for (int kr = 0; kr < 3; ++kr) {
                    const float* row = &s_in[(y + kr) * INS + xx];
#pragma unroll
                    for (int kc = 0; kc < 7; ++kc) {
                        float v = row[kc];
                        float4 wv = w1v[(kr * 7 + kc) * 4 + g];
                        acc.x += v * wv.x; acc.y += v * wv.y;
                        acc.z += v * wv.z; acc.w += v * wv.w;
                    }
                }
                {
                    const float* row = &s_in[(y + 3) * INS + xx];
#pragma unroll
                    for (int kc = 0; kc < 3; ++kc) {
                        float v = row[kc];
                        float4 wv = w1v[(21 + kc) * 4 + g];
                        acc.x += v * wv.x; acc.y += v * wv.y;
                        acc.z += v * wv.z; acc.w += v * wv.w;
                    }
                }
                acc.x = fmaxf(acc.x, 0.f); acc.y = fmaxf(acc.y, 0.f);
                acc.z = fmaxf(acc.z, 0.f); acc.w = fmaxf(acc.w, 0.f);
                packed.x = bf_rne(acc.x) | (bf_rne(acc.y) << 16);
                packed.y = bf_rne(acc.z) | (bf_rne(acc.w) << 16);
            } else {
                packed.x = 0u; packed.y = 0u;
            }
            ((uint2*)s_h1)[((g2 * H1H + y) * H1W + xx) * 2 + half] = packed;
        }
    }
    __syncthreads();

    // ---------------- Phase 2: L2 3x3 masked conv (wave = 4 out-ch, 8 px/thread) ----------------
    {
        const float4 bias2 = ((const float4*)s_b2)[wave];
        const float4* w2v = (const float4*)s_w2;     // [(tap*16+i)*4 + wave]
        const uint4* h1v = (const uint4*)s_h1;       // [(g2*18+y)*34+x] = 8 bf16 ch

        float4 acc[8];
        int base[8];
#pragma unroll
        for (int j = 0; j < 8; ++j) {
            int p = lane + 64 * j;
            base[j] = ((p >> 5) + 1) * H1W + (p & 31) + 1;
            acc[j] = bias2;
        }

#pragma unroll
        for (int k = 0; k < 5; ++k) {
            const int dy = (k < 3) ? -1 : 0;
            const int dx = (k < 3) ? (k - 1) : (k - 4);
            const int doff = dy * H1W + dx;
#pragma unroll
            for (int g2 = 0; g2 < 2; ++g2) {
                float4 wv[8];
                const int wbase = (k * 16 + g2 * 8) * 4 + wave;
#pragma unroll
                for (int ii = 0; ii < 8; ++ii) wv[ii] = w2v[wbase + ii * 4];
                const int hbase = g2 * (H1H * H1W) + doff;
#pragma unroll
                for (int j = 0; j < 8; ++j) {
                    uint4 hv = h1v[hbase + base[j]];
                    float hh[8];
                    hh[0] = bf_lo(hv.x); hh[1] = bf_hi(hv.x);
                    hh[2] = bf_lo(hv.y); hh[3] = bf_hi(hv.y);
                    hh[4] = bf_lo(hv.z); hh[5] = bf_hi(hv.z);
                    hh[6] = bf_lo(hv.w); hh[7] = bf_hi(hv.w);
#pragma unroll
                    for (int ii = 0; ii < 8; ++ii) {
                        acc[j].x += hh[ii] * wv[ii].x;
                        acc[j].y += hh[ii] * wv[ii].y;
                        acc[j].z += hh[ii] * wv[ii].z;
                        acc[j].w += hh[ii] * wv[ii].w;
                    }
                }
            }
        }

        // ReLU + partial dot with w3 (this wave's 4 out-channels)
        const float4 w34 = ((const float4*)s_w3)[wave];
#pragma unroll
        for (int j = 0; j < 8; ++j) {
            float s = fmaxf(acc[j].x, 0.f) * w34.x + fmaxf(acc[j].y, 0.f) * w34.y
                    + fmaxf(acc[j].z, 0.f) * w34.z + fmaxf(acc[j].w, 0.f) * w34.w;
            s_red[wave * (TH * TW) + lane + 64 * j] = s;
        }
    }
    __syncthreads();

    // ---------------- Phase 3: cross-wave reduce + bias + sigmoid + store ----------------
    {
        const float bias3 = b3[0];
        for (int p = t; p < TH * TW; p += 256) {
            float s = s_red[p] + s_red[512 + p] + s_red[1024 + p] + s_red[1536 + p] + bias3;
            float r = 1.f / (1.f + __expf(-s));
            int gy = ty0 + (p >> 5), gx = tx0 + (p & 31);
            out[img * (IMG_H * IMG_W) + gy * IMG_W + gx] = r;
        }
    }
}

extern "C" void kernel_launch(void* const* d_in, const int* in_sizes, int n_in,
                              void* d_out, int out_size, void* d_ws, size_t ws_size,
                              hipStream_t stream) {
    const float* x  = (const float*)d_in[0];
    const float* w1 = (const float*)d_in[1];
    const float* b1 = (const float*)d_in[2];
    const float* w2 = (const float*)d_in[3];
    const float* b2 = (const float*)d_in[4];
    const float* w3 = (const float*)d_in[5];
    const float* b3 = (const float*)d_in[6];
    float* out = (float*)d_out;

    dim3 grid(8, 1024);   // 2x4 tiles per image, 1024 images
    dim3 block(256);
    hipLaunchKernelGGL(pixelcnn_fused, grid, block, 0, stream,
                       x, w1, b1, w2, b2, w3, b3, out);
}

// Round 3
// 168.239 us; speedup vs baseline: 1.9162x; 1.9162x over previous
//
#include <hip/hip_runtime.h>

typedef _Float16 half8 __attribute__((ext_vector_type(8)));
typedef float floatx4 __attribute__((ext_vector_type(4)));

#define IMG_H 64
#define IMG_W 64
#define TH 16
#define TW 32
#define INH 21   // input rows staged: ty0-4 .. ty0+16
#define INW 40   // input cols staged: tx0-4 .. tx0+35
#define H1H 18   // h1 rows: ty0-1 .. ty0+16
#define H1W 34   // h1 cols: tx0-1 .. tx0+32
#define NH1 (H1H * H1W)   // 612

__global__ __launch_bounds__(256, 4) void pixelcnn_mfma(
    const float* __restrict__ x,
    const float* __restrict__ w1, const float* __restrict__ b1,
    const float* __restrict__ w2, const float* __restrict__ b2,
    const float* __restrict__ w3, const float* __restrict__ b3,
    float* __restrict__ out)
{
    // LDS budget: 3360 + 1024 + 3072 + 192 + 19584 + 8192 = 35424 B -> 4 blocks/CU
    __shared__ __align__(16) float     s_in[INH * INW];   // fp32 x tile
    __shared__ __align__(16) _Float16  s_w1t[16 * 32];    // B1 [n][k], k padded to 32
    __shared__ __align__(16) _Float16  s_w2t[16 * 96];    // B2 [n][k], k=tap*16+ic padded to 96
    __shared__ __align__(16) float     s_b1[16], s_b2[16], s_w3[16];
    __shared__ __align__(16) uint4     s_h1[2 * NH1];     // h1 f16: [icblk][y][x][8ch] (16B/entry)
    __shared__ __align__(16) float     s_red[512 * 4];    // per-px 4 partial n-sums

    const int t    = threadIdx.x;
    const int lane = t & 63;
    const int wave = t >> 6;
    const int n    = lane & 15;   // MFMA col (out-channel) & A-row field
    const int quad = lane >> 4;   // MFMA k-slice / D-row group
    const int img  = blockIdx.y;
    const int btile = blockIdx.x;
    const int ty0 = (btile >> 1) * TH;
    const int tx0 = (btile & 1) * TW;

    const float* xim = x + img * (IMG_H * IMG_W);

    // ---------------- Phase 0: stage input (fp32) + weights (f16, fragment-friendly) ----------
    for (int idx = t; idx < INH * INW; idx += 256) {
        int r = idx / INW, c = idx - r * INW;
        int gy = ty0 - 4 + r, gx = tx0 - 4 + c;
        float v = 0.f;
        if ((unsigned)gy < IMG_H && (unsigned)gx < IMG_W) v = xim[gy * IMG_W + gx];
        s_in[idx] = v;
    }
    for (int idx = t; idx < 16 * 32; idx += 256) {        // w1t[n][k]: masked taps k=0..23
        int nn = idx >> 5, k = idx & 31;
        s_w1t[idx] = (k < 24) ? (_Float16)w1[nn * 49 + k] : (_Float16)0.f;
    }
    for (int idx = t; idx < 16 * 96; idx += 256) {        // w2t[n][k]: k=tap*16+ic, taps 0..4
        int nn = idx / 96, k = idx - nn * 96;
        int tap = k >> 4, ic = k & 15;
        s_w2t[idx] = (tap < 5) ? (_Float16)w2[(nn * 16 + ic) * 9 + tap] : (_Float16)0.f;
    }
    if (t < 16) { s_b1[t] = b1[t]; s_b2[t] = b2[t]; s_w3[t] = w3[t]; }
    __syncthreads();

    // ---------------- Phase 1: L1 7x7 masked conv via MFMA -> relu -> f16 s_h1 ----------------
    {
        half8 bfrag = *(const half8*)&s_w1t[n * 32 + quad * 8];  // B[k][n], this lane's slice
        int koff[8];
        if (quad < 3) {
#pragma unroll
            for (int j = 0; j < 8; ++j) {
                int k = quad * 8 + j;
                int kr = (k < 21) ? (k / 7) : 3;
                int kc = (k < 21) ? (k - kr * 7) : (k - 21);
                koff[j] = kr * INW + kc;
            }
        }
        const float bias1 = s_b1[n];
        for (int tile = wave; tile < 39; tile += 4) {
            int pm = tile * 16 + n;                  // A-row m pixel
            int p = (pm < NH1 - 1) ? pm : (NH1 - 1); // clamp for safe addressing
            int py = p / H1W, px = p - py * H1W;
            int abase = py * INW + px;               // s_in[py+kr][px+kc] = abase + koff
            half8 a;
            if (quad < 3) {
#pragma unroll
                for (int j = 0; j < 8; ++j) a[j] = (_Float16)s_in[abase + koff[j]];
            } else {
#pragma unroll
                for (int j = 0; j < 8; ++j) a[j] = (_Float16)0.f;
            }
            floatx4 acc = {bias1, bias1, bias1, bias1};
            acc = __builtin_amdgcn_mfma_f32_16x16x32_f16(a, bfrag, acc, 0, 0, 0);
            // D: row = quad*4+r (pixel), col = n (channel)
#pragma unroll
            for (int r = 0; r < 4; ++r) {
                int pp = tile * 16 + quad * 4 + r;
                if (pp < NH1) {
                    int wy = pp / H1W, wx = pp - wy * H1W;
                    int gy = ty0 - 1 + wy, gx = tx0 - 1 + wx;
                    float v = fmaxf(acc[r], 0.f);
                    _Float16 hv = ((unsigned)gy < IMG_H && (unsigned)gx < IMG_W)
                                  ? (_Float16)v : (_Float16)0.f;
                    ((_Float16*)s_h1)[(((n >> 3) * NH1 + pp) << 3) + (n & 7)] = hv;
                }
            }
        }
    }
    __syncthreads();

    // ---------------- Phase 2: L2 3x3 masked conv via MFMA (K=80 -> 3 frags) -----------------
    {
        half8 b2f[3];
#pragma unroll
        for (int f = 0; f < 3; ++f)
            b2f[f] = *(const half8*)&s_w2t[n * 96 + f * 32 + quad * 8];
        const float bias2 = s_b2[n];
        const float w3v = s_w3[n];

        int foff[3]; bool factive[3];
#pragma unroll
        for (int f = 0; f < 3; ++f) {
            int tq = f * 4 + quad;        // 2 k-halves per tap
            int tap = tq >> 1, icb = tq & 1;
            factive[f] = (tap < 5);
            int dy = (tap < 3) ? -1 : 0;
            int dx = (tap < 3) ? (tap - 1) : (tap - 4);
            foff[f] = icb * NH1 + dy * H1W + dx;
        }

        for (int tile = wave; tile < 32; tile += 4) {
            int y = tile >> 1, x0 = (tile & 1) * 16;
            int base = (y + 1) * H1W + (x0 + n + 1);   // h1 entry for this lane's m-pixel
            floatx4 acc = {bias2, bias2, bias2, bias2};
#pragma unroll
            for (int f = 0; f < 3; ++f) {
                half8 a;
                if (factive[f]) {
                    a = *(const half8*)&s_h1[base + foff[f]];  // one b128 = 8 f16 channels
                } else {
#pragma unroll
                    for (int j = 0; j < 8; ++j) a[j] = (_Float16)0.f;
                }
                acc = __builtin_amdgcn_mfma_f32_16x16x32_f16(a, b2f[f], acc, 0, 0, 0);
            }
            // Epilogue: relu * w3[n], reduce over n (16 lanes) down to 4 partials
            float s[4];
#pragma unroll
            for (int r = 0; r < 4; ++r) s[r] = fmaxf(acc[r], 0.f) * w3v;
#pragma unroll
            for (int r = 0; r < 4; ++r) {
                s[r] += __shfl_xor(s[r], 8);
                s[r] += __shfl_xor(s[r], 4);
            }
            if (n < 4) {
#pragma unroll
                for (int r = 0; r < 4; ++r) {
                    int pp = tile * 16 + quad * 4 + r;   // output px 0..511
                    s_red[pp * 4 + n] = s[r];
                }
            }
        }
    }
    __syncthreads();

    // ---------------- Phase 3: final 4-way sum + bias + sigmoid + store ----------------------
    {
        const float bias3 = b3[0];
        for (int p = t; p < 512; p += 256) {
            float4 v = *(const float4*)&s_red[p * 4];
            float ssum = v.x + v.y + v.z + v.w + bias3;
            float r = 1.f / (1.f + __expf(-ssum));
            int gy = ty0 + (p >> 5), gx = tx0 + (p & 31);
            out[img * (IMG_H * IMG_W) + gy * IMG_W + gx] = r;
        }
    }
}

extern "C" void kernel_launch(void* const* d_in, const int* in_sizes, int n_in,
                              void* d_out, int out_size, void* d_ws, size_t ws_size,
                              hipStream_t stream) {
    const float* x  = (const float*)d_in[0];
    const float* w1 = (const float*)d_in[1];
    const float* b1 = (const float*)d_in[2];
    const float* w2 = (const float*)d_in[3];
    const float* b2 = (const float*)d_in[4];
    const float* w3 = (const float*)d_in[5];
    const float* b3 = (const float*)d_in[6];
    float* out = (float*)d_out;

    dim3 grid(8, 1024);   // 2x4 tiles per image, 1024 images
    dim3 block(256);
    hipLaunchKernelGGL(pixelcnn_mfma, grid, block, 0, stream,
                       x, w1, b1, w2, b2, w3, b3, out);
}

// Round 4
// 145.345 us; speedup vs baseline: 2.2181x; 1.1575x over previous
//
#include <hip/hip_runtime.h>

typedef _Float16 half8 __attribute__((ext_vector_type(8)));
typedef _Float16 half4 __attribute__((ext_vector_type(4)));
typedef float floatx4 __attribute__((ext_vector_type(4)));

#define IMG_H 64
#define IMG_W 64
#define TH 16
#define TW 32
#define INH 21   // input rows staged: ty0-4 .. ty0+16
#define INW 40   // input cols staged: tx0-4 .. tx0+35
#define H1H 18   // h1 rows: ty0-1 .. ty0+16
#define H1W 34   // h1 cols: tx0-1 .. tx0+32
#define NH1 (H1H * H1W)   // 612

__global__ __launch_bounds__(256, 5) void pixelcnn_mfma2(
    const float* __restrict__ x,
    const float* __restrict__ w1, const float* __restrict__ b1,
    const float* __restrict__ w2, const float* __restrict__ b2,
    const float* __restrict__ w3, const float* __restrict__ b3,
    float* __restrict__ out)
{
    // LDS: 3360 + 1024 + 3072 + 208 + 19584 = 27248 B -> 5 blocks/CU
    __shared__ __align__(16) float     s_in[INH * INW];   // fp32 x tile
    __shared__ __align__(16) _Float16  s_w1t[16 * 32];    // [ch][k], k padded to 32
    __shared__ __align__(16) _Float16  s_w2t[16 * 96];    // [ch][k], k=tap*16+ic padded to 96
    __shared__ __align__(16) float     s_b1[16], s_b2[16], s_w3[16];
    __shared__ float                   s_b3;
    __shared__ __align__(16) _Float16  s_h1[NH1 * 16];    // h1: [px][16ch] f16 (32 B/px)

    const int t    = threadIdx.x;
    const int lane = t & 63;
    const int wave = t >> 6;
    const int n    = lane & 15;   // A-row (=channel for weights) AND B-col (=pixel) field
    const int quad = lane >> 4;   // k-slice group / D-row quad
    const int img  = blockIdx.y;
    const int btile = blockIdx.x;
    const int ty0 = (btile >> 1) * TH;
    const int tx0 = (btile & 1) * TW;

    const float* xim = x + img * (IMG_H * IMG_W);

    // ---------------- Phase 0: stage input (fp32) + weights (f16) ----------------
    for (int idx = t; idx < INH * INW; idx += 256) {
        int r = idx / INW, c = idx - r * INW;
        int gy = ty0 - 4 + r, gx = tx0 - 4 + c;
        float v = 0.f;
        if ((unsigned)gy < IMG_H && (unsigned)gx < IMG_W) v = xim[gy * IMG_W + gx];
        s_in[idx] = v;
    }
    for (int idx = t; idx < 16 * 32; idx += 256) {        // w1t[ch][k]: masked taps k=0..23
        int nn = idx >> 5, k = idx & 31;
        s_w1t[idx] = (k < 24) ? (_Float16)w1[nn * 49 + k] : (_Float16)0.f;
    }
    for (int idx = t; idx < 16 * 96; idx += 256) {        // w2t[ch][k]: k=tap*16+ic, taps 0..4
        int nn = idx / 96, k = idx - nn * 96;
        int tap = k >> 4, ic = k & 15;
        s_w2t[idx] = (tap < 5) ? (_Float16)w2[(nn * 16 + ic) * 9 + tap] : (_Float16)0.f;
    }
    if (t < 16) { s_b1[t] = b1[t]; s_b2[t] = b2[t]; s_w3[t] = w3[t]; }
    if (t == 16) { s_b3 = b3[0]; }
    __syncthreads();

    // ---------------- Phase 1: L1 7x7 via MFMA (D = W*im2col -> [ch][px]) ----------------
    {
        half8 afrag = *(const half8*)&s_w1t[n * 32 + quad * 8];  // A[m=ch][k] slice
        const bool qact = (quad < 3);                             // k>=24 is zero-padded
        int koff[8];
        if (qact) {
#pragma unroll
            for (int j = 0; j < 8; ++j) {
                int k = quad * 8 + j;
                int kr = (k < 21) ? (k / 7) : 3;
                int kc = (k < 21) ? (k - kr * 7) : (k - 21);
                koff[j] = kr * INW + kc;
            }
        }
        const floatx4 bias1 = ((const floatx4*)s_b1)[quad];       // bias for rows quad*4+r
        for (int tile = wave; tile < 39; tile += 4) {
            int pm = tile * 16 + n;                   // this lane's B-col pixel
            int p = (pm < NH1) ? pm : (NH1 - 1);      // clamp (lanes n>=4 in last tile)
            int py = p / H1W, px = p - py * H1W;
            int abase = py * INW + px;
            half8 b;
            if (qact) {
#pragma unroll
                for (int j = 0; j < 8; ++j) b[j] = (_Float16)s_in[abase + koff[j]];
            } else {
#pragma unroll
                for (int j = 0; j < 8; ++j) b[j] = (_Float16)0.f;
            }
            floatx4 acc = bias1;
            acc = __builtin_amdgcn_mfma_f32_16x16x32_f16(afrag, b, acc, 0, 0, 0);
            // D: row = ch = quad*4+r, col = px = n  -> one b64 write of 4 channels
            int gy = ty0 - 1 + py, gx = tx0 - 1 + px;
            bool inimg = ((unsigned)gy < IMG_H) && ((unsigned)gx < IMG_W);
            half4 hv;
#pragma unroll
            for (int r = 0; r < 4; ++r)
                hv[r] = inimg ? (_Float16)fmaxf(acc[r], 0.f) : (_Float16)0.f;
            if (pm < NH1)
                *(half4*)&s_h1[p * 16 + quad * 4] = hv;
        }
    }
    __syncthreads();

    // ---------------- Phase 2: L2 3x3 via MFMA (D = W2*h1col -> [ch][px]) + fused tail ------
    {
        half8 wfrag[3];
#pragma unroll
        for (int f = 0; f < 3; ++f)
            wfrag[f] = *(const half8*)&s_w2t[n * 96 + f * 32 + quad * 8];
        const floatx4 bias2 = ((const floatx4*)s_b2)[quad];
        const floatx4 w3q   = ((const floatx4*)s_w3)[quad];
        const float bias3 = s_b3;
        const int tqh = quad >> 1;         // which tap within this frag's k-range
        const int icq = (quad & 1) * 8;    // channel sub-block
        // frag f covers taps {2f, 2f+1}: tap = 2f + tqh
        // tap deltas: 0:(-1,-1) 1:(-1,0) 2:(-1,1) 3:(0,-1) 4:(0,0)
        const int off0 = -H1W - 1 + tqh;               // taps 0,1
        const int off1 = tqh ? -1 : (-H1W + 1);        // taps 2,3
        const bool act2 = (quad < 2);                  // tap 4 valid, tap 5 padded->zero
        float* outim = out + img * (IMG_H * IMG_W);

        for (int tile = wave; tile < 32; tile += 4) {
            int y = tile >> 1, x0 = (tile & 1) * 16;
            int E = (y + 1) * H1W + x0 + n + 1;        // this lane's pixel in h1 coords
            floatx4 acc = bias2;
            half8 bf;
            bf = *(const half8*)&s_h1[(E + off0) * 16 + icq];
            acc = __builtin_amdgcn_mfma_f32_16x16x32_f16(wfrag[0], bf, acc, 0, 0, 0);
            bf = *(const half8*)&s_h1[(E + off1) * 16 + icq];
            acc = __builtin_amdgcn_mfma_f32_16x16x32_f16(wfrag[1], bf, acc, 0, 0, 0);
            if (act2) {
                bf = *(const half8*)&s_h1[E * 16 + icq];
            } else {
#pragma unroll
                for (int j = 0; j < 8; ++j) bf[j] = (_Float16)0.f;
            }
            acc = __builtin_amdgcn_mfma_f32_16x16x32_f16(wfrag[2], bf, acc, 0, 0, 0);

            // per-lane partial: 4 channels of pixel n; then sum over quads
            float s = fmaxf(acc[0], 0.f) * w3q[0];
            s = fmaf(fmaxf(acc[1], 0.f), w3q[1], s);
            s = fmaf(fmaxf(acc[2], 0.f), w3q[2], s);
            s = fmaf(fmaxf(acc[3], 0.f), w3q[3], s);
            s += __shfl_xor(s, 16);
            s += __shfl_xor(s, 32);
            if (lane < 16) {
                float r = 1.f / (1.f + __expf(-(s + bias3)));
                outim[(ty0 + y) * IMG_W + tx0 + x0 + n] = r;
            }
        }
    }
}

extern "C" void kernel_launch(void* const* d_in, const int* in_sizes, int n_in,
                              void* d_out, int out_size, void* d_ws, size_t ws_size,
                              hipStream_t stream) {
    const float* x  = (const float*)d_in[0];
    const float* w1 = (const float*)d_in[1];
    const float* b1 = (const float*)d_in[2];
    const float* w2 = (const float*)d_in[3];
    const float* b2 = (const float*)d_in[4];
    const float* w3 = (const float*)d_in[5];
    const float* b3 = (const float*)d_in[6];
    float* out = (float*)d_out;

    dim3 grid(8, 1024);   // 2x4 tiles per image, 1024 images
    dim3 block(256);
    hipLaunchKernelGGL(pixelcnn_mfma2, grid, block, 0, stream,
                       x, w1, b1, w2, b2, w3, b3, out);
}

// Round 6
// 121.099 us; speedup vs baseline: 2.6622x; 1.2002x over previous
//
#include <hip/hip_runtime.h>

typedef _Float16 half8  __attribute__((ext_vector_type(8)));
typedef __fp16   fp16x2 __attribute__((ext_vector_type(2)));   // cvt_pkrtz native type
typedef float    floatx4 __attribute__((ext_vector_type(4)));

#define IMG_H 64
#define IMG_W 64
#define TH 16
#define TW 32
#define INH 21            // input rows staged: ty0-4 .. ty0+16
#define INW 40            // input cols staged: tx0-4 .. tx0+35
#define H1W 34            // h1 cols: tx0-1 .. tx0+32
#define NH1 612           // 18*34 real h1 pixels
#define NPX 624           // padded (writes up to p=623 land in never-read slots)
#define PLANE_B (NPX*16)  // 9984 B per channel-half plane

__device__ __forceinline__ unsigned pk2u(float a, float b) {
    fp16x2 h = __builtin_amdgcn_cvt_pkrtz(a, b);
    return __builtin_bit_cast(unsigned, h);
}

__global__ __launch_bounds__(256, 5) void pixelcnn_mfma3(
    const float* __restrict__ x,
    const float* __restrict__ w1, const float* __restrict__ b1,
    const float* __restrict__ w2, const float* __restrict__ b2,
    const float* __restrict__ w3, const float* __restrict__ b3,
    float* __restrict__ out)
{
    // LDS: 3392 + 1024 + 3072 + 196 + 19968 = ~27.7 KB -> 5 blocks/CU
    __shared__ __align__(16) float     s_in[INH*INW + 8];   // +8 pad for j=7 over-read
    __shared__ __align__(16) _Float16  s_w1t[16*32];        // [ch][k], k=(kr=q)*8+(kc=j), pad->0
    __shared__ __align__(16) _Float16  s_w2t[16*96];        // [ch][k], k=tap*16+ic, pad->0
    __shared__ __align__(16) float     s_b1[16], s_b2[16], s_w3[16];
    __shared__ float                   s_b3;
    __shared__ __align__(16) unsigned  s_h1[2*NPX*4];       // [c2][px][8ch f16], 16 B/px/plane

    const int t    = threadIdx.x;
    const int lane = t & 63;
    const int wave = t >> 6;
    const int n    = lane & 15;   // MFMA: weight-row ch field & B-col pixel field
    const int quad = lane >> 4;   // MFMA k-slice group / D-row quad
    const int img  = blockIdx.y;
    const int btile = blockIdx.x;
    const int ty0 = (btile >> 1) * TH;
    const int tx0 = (btile & 1) * TW;

    const float* xim = x + img * (IMG_H * IMG_W);

    // ---------------- Phase 0: stage input (float4) + weights (f16, permuted) ----------------
    if (t < 212) {
        if (t < 210) {                       // 21 rows x 10 float4-chunks
            int r = t / 10, c4 = (t - r * 10) * 4;
            int gy = ty0 - 4 + r, gx = tx0 - 4 + c4;   // gx ≡ 0 mod 4 -> chunk fully in/out
            float4 v = {0.f, 0.f, 0.f, 0.f};
            if ((unsigned)gy < IMG_H && (unsigned)gx < IMG_W)
                v = *(const float4*)&xim[gy * IMG_W + gx];
            *(float4*)&s_in[r * INW + c4] = v;
        } else {                             // zero the 8-float pad
            *(float4*)&s_in[INH * INW + (t - 210) * 4] = float4{0.f, 0.f, 0.f, 0.f};
        }
    }
    {
        int ch = t >> 4, l = t & 15;         // 256 threads = 16 ch x 16 lanes
        const float* w1c = w1 + ch * 49;
#pragma unroll
        for (int j2 = 0; j2 < 2; ++j2) {     // w1t: k = q*8+j <-> tap (kr=q, kc=j)
            int k = l + 16 * j2, q = k >> 3, jj = k & 7;
            float v = 0.f;
            if (q < 3)      { if (jj < 7) v = w1c[q * 7 + jj]; }
            else            { if (jj < 3) v = w1c[21 + jj];    }
            s_w1t[ch * 32 + k] = (_Float16)v;
        }
        const float* w2cl = w2 + (ch * 16 + l) * 9;   // w2t: k = tap*16 + ic(=l)
#pragma unroll
        for (int j = 0; j < 6; ++j)
            s_w2t[ch * 96 + j * 16 + l] = (j < 5) ? (_Float16)w2cl[j] : (_Float16)0.f;
    }
    if (t < 16) { s_b1[t] = b1[t]; s_b2[t] = b2[t]; s_w3[t] = w3[t]; }
    if (t == 16) s_b3 = b3[0];
    __syncthreads();

    // ---------------- Phase 1: L1 7x7 via MFMA, contiguous row-gather ----------------
    {
        const half8 afrag = *(const half8*)&s_w1t[n * 32 + quad * 8];
        const floatx4 bias1 = ((const floatx4*)s_b1)[quad];
        int p  = wave * 16 + n;
        int py = p / H1W, px = p - py * H1W;
        int rdq = (py + quad) * INW + px;     // this lane reads s_in row py+quad, cols px..px+7
        int gy = ty0 - 1 + py;
        int gx = tx0 - 1 + px;
        unsigned wd = (unsigned)((quad >> 1) * (NPX * 4) + p * 4 + (quad & 1) * 2); // dword idx

        for (int tile = wave; tile < 39; tile += 4) {
            float v0 = s_in[rdq    ], v1 = s_in[rdq + 1], v2 = s_in[rdq + 2], v3 = s_in[rdq + 3];
            float v4 = s_in[rdq + 4], v5 = s_in[rdq + 5], v6 = s_in[rdq + 6], v7 = s_in[rdq + 7];
            uint4 bu;
            bu.x = pk2u(v0, v1);
            bu.y = pk2u(v2, v3);
            bu.z = pk2u(v4, v5);
            bu.w = pk2u(v6, v7);
            half8 b = __builtin_bit_cast(half8, bu);
            floatx4 acc = bias1;
            acc = __builtin_amdgcn_mfma_f32_16x16x32_f16(afrag, b, acc, 0, 0, 0);
            // D: row = ch = quad*4+r, col = px = n
            bool inimg = ((unsigned)gy < IMG_H) & ((unsigned)gx < IMG_W);
            unsigned lo = pk2u(fmaxf(acc[0], 0.f), fmaxf(acc[1], 0.f));
            unsigned hi = pk2u(fmaxf(acc[2], 0.f), fmaxf(acc[3], 0.f));
            lo = inimg ? lo : 0u;
            hi = inimg ? hi : 0u;
            uint2 wv; wv.x = lo; wv.y = hi;
            *(uint2*)&s_h1[wd] = wv;          // b64, 2-way banks (free)
            // advance 64 pixels: py += 1 (+wrap), px += 30
            px += 30; gy += 1; rdq += 70; wd += 256;
            if (px >= H1W) { px -= H1W; gy += 1; rdq += 6; }
            gx = tx0 - 1 + px;
        }
    }
    __syncthreads();

    // ---------------- Phase 2: L2 3x3 via MFMA + fused relu/w3-dot/sigmoid/store ----------
    {
        const half8 w2f0 = *(const half8*)&s_w2t[n * 96 +  0 + quad * 8];
        const half8 w2f1 = *(const half8*)&s_w2t[n * 96 + 32 + quad * 8];
        const half8 w2f2 = *(const half8*)&s_w2t[n * 96 + 64 + quad * 8];
        const floatx4 bias2 = ((const floatx4*)s_b2)[quad];
        const floatx4 w3q   = ((const floatx4*)s_w3)[quad];
        const float bias3 = s_b3;
        const int y0 = wave >> 1, x0 = (wave & 1) * 16;  // per-wave fixed column half
        const int tqh = quad >> 1, plane = quad & 1;
        const int E0 = (y0 + 1) * H1W + x0 + n + 1;      // lane pixel in h1 coords (k=0)
        // taps: f0 -> {(-1,-1),(-1,0)}, f1 -> {(-1,1),(0,-1)}, f2 -> {(0,0), pad(A=0)}
        const char* h1b = (const char*)s_h1 + plane * PLANE_B;
        const char* a0 = h1b + (E0 - 35 + tqh) * 16;
        const char* a1 = h1b + (E0 + (tqh ? -1 : -33)) * 16;
        const char* a2 = h1b + E0 * 16;                  // tqh=1 dummy (A zeros)
        float* optr = out + ((img * IMG_H) + ty0 + y0) * IMG_W + tx0 + x0 + n;

#pragma unroll
        for (int k = 0; k < 8; ++k) {                    // y = y0 + 2k; ΔE=68 -> 1088 B imm
            floatx4 acc = bias2;
            acc = __builtin_amdgcn_mfma_f32_16x16x32_f16(w2f0, *(const half8*)(a0 + k * 1088), acc, 0, 0, 0);
            acc = __builtin_amdgcn_mfma_f32_16x16x32_f16(w2f1, *(const half8*)(a1 + k * 1088), acc, 0, 0, 0);
            acc = __builtin_amdgcn_mfma_f32_16x16x32_f16(w2f2, *(const half8*)(a2 + k * 1088), acc, 0, 0, 0);
            float s = fmaxf(acc[0], 0.f) * w3q[0];
            s = fmaf(fmaxf(acc[1], 0.f), w3q[1], s);
            s = fmaf(fmaxf(acc[2], 0.f), w3q[2], s);
            s = fmaf(fmaxf(acc[3], 0.f), w3q[3], s);
            s += __shfl_xor(s, 16);
            s += __shfl_xor(s, 32);
            if (lane < 16) {
                float r = 1.f / (1.f + __expf(-(s + bias3)));
                *(float*)((char*)optr + k * 512) = r;    // Δrow=2 -> 512 B imm
            }
        }
    }
}

extern "C" void kernel_launch(void* const* d_in, const int* in_sizes, int n_in,
                              void* d_out, int out_size, void* d_ws, size_t ws_size,
                              hipStream_t stream) {
    const float* x  = (const float*)d_in[0];
    const float* w1 = (const float*)d_in[1];
    const float* b1 = (const float*)d_in[2];
    const float* w2 = (const float*)d_in[3];
    const float* b2 = (const float*)d_in[4];
    const float* w3 = (const float*)d_in[5];
    const float* b3 = (const float*)d_in[6];
    float* out = (float*)d_out;

    dim3 grid(8, 1024);   // 2x4 tiles per image, 1024 images
    dim3 block(256);
    hipLaunchKernelGGL(pixelcnn_mfma3, grid, block, 0, stream,
                       x, w1, b1, w2, b2, w3, b3, out);
}